// Round 6
// baseline (168.670 us; speedup 1.0000x reference)
//
#include <hip/hip_runtime.h>

typedef unsigned short u16;
typedef unsigned int   u32;

typedef __attribute__((ext_vector_type(8))) short short8;
typedef __attribute__((ext_vector_type(4))) float floatx4;

// ---- f32 -> bf16 (RNE) ----
__device__ __forceinline__ u16 f2bf(float f) {
    u32 u = __float_as_uint(f);
    u = u + 0x7fffu + ((u >> 16) & 1u);
    return (u16)(u >> 16);
}

// pack two f32 -> two bf16 (round-to-nearest-away) in one v_perm
__device__ __forceinline__ u32 pack2bf(float s0, float s1) {
    u32 a = __float_as_uint(s0) + 0x8000u;
    u32 b = __float_as_uint(s1) + 0x8000u;
    return __builtin_amdgcn_perm(b, a, 0x07060302u);  // {b.hi16, a.hi16}
}

__device__ __forceinline__ floatx4 mfma16(short8 a, short8 b, floatx4 c) {
    return __builtin_amdgcn_mfma_f32_16x16x32_bf16(a, b, c, 0, 0, 0);
}

// ---- prep: LDS-transpose weight tiles into per-thread MFMA B-fragment streams.
// W1frag[kt]: [(n4*64+lane)*32 + f*8 + ji] = bf16(W1[(7+kt*32+lq*8+ji)*256 + n4*64+f*16+lr])
// W2frag[kt]: same with wv in place of n4 (4 frags), W2 rows kt*32..
// W3frag[kt]: [(wv*64+lane)*16 + j*8 + ji] = bf16(W3[(kt*32+lq*8+ji)*128 + wv*32+j*16+lr])
__global__ __launch_bounds__(256) void k_prep(
    const float* __restrict__ W1, const float* __restrict__ W2,
    const float* __restrict__ W3, u16* __restrict__ W1frag,
    u16* __restrict__ W2frag, u16* __restrict__ W3frag) {
    __shared__ float ws[32][257];
    const int t = threadIdx.x;
    const int mode = blockIdx.x;
    const int lane = t & 63, grp = t >> 6;   // grp = n4 / wv
    const int lr = lane & 15, lq = lane >> 4;

    if (mode < 64) {            // W1 tile kt=mode
        const int kt = mode;
#pragma unroll
        for (int i = 0; i < 32; ++i) {
            int idx2 = t + i * 256;
            ws[idx2 >> 8][idx2 & 255] = W1[(7 + kt * 32 + (idx2 >> 8)) * 256 + (idx2 & 255)];
        }
        __syncthreads();
        u16 arr[32];
#pragma unroll
        for (int f = 0; f < 4; ++f)
#pragma unroll
            for (int ji = 0; ji < 8; ++ji)
                arr[f * 8 + ji] = f2bf(ws[lq * 8 + ji][grp * 64 + f * 16 + lr]);
        uint4* dst = (uint4*)(W1frag + kt * 8192 + t * 32);
#pragma unroll
        for (int q = 0; q < 4; ++q) dst[q] = ((const uint4*)arr)[q];
    } else if (mode < 72) {     // W2 tile
        const int kt = mode - 64;
#pragma unroll
        for (int i = 0; i < 32; ++i) {
            int idx2 = t + i * 256;
            ws[idx2 >> 8][idx2 & 255] = W2[(kt * 32 + (idx2 >> 8)) * 256 + (idx2 & 255)];
        }
        __syncthreads();
        u16 arr[32];
#pragma unroll
        for (int f = 0; f < 4; ++f)
#pragma unroll
            for (int ji = 0; ji < 8; ++ji)
                arr[f * 8 + ji] = f2bf(ws[lq * 8 + ji][grp * 64 + f * 16 + lr]);
        uint4* dst = (uint4*)(W2frag + kt * 8192 + t * 32);
#pragma unroll
        for (int q = 0; q < 4; ++q) dst[q] = ((const uint4*)arr)[q];
    } else {                    // W3 tile
        const int kt = mode - 72;
#pragma unroll
        for (int i = 0; i < 16; ++i) {
            int idx2 = t + i * 256;
            ws[idx2 >> 7][idx2 & 127] = W3[(kt * 32 + (idx2 >> 7)) * 128 + (idx2 & 127)];
        }
        __syncthreads();
        u16 arr[16];
#pragma unroll
        for (int j = 0; j < 2; ++j)
#pragma unroll
            for (int ji = 0; ji < 8; ++ji)
                arr[j * 8 + ji] = f2bf(ws[lq * 8 + ji][grp * 32 + j * 16 + lr]);
        uint4* dst = (uint4*)(W3frag + kt * 4096 + t * 16);
        dst[0] = ((const uint4*)arr)[0];
        dst[1] = ((const uint4*)arr)[1];
    }
}

// ---- kernel 1: h1 = lrelu( [u,norm,proj,dots] @ W1 + b1 )
// 512 thr, M=64 x N=256 per block; waves = k-split2 x n-split4.
// Dots tile stored FRAGMENT-LINEAR in LDS (lane-consecutive 16B chunks):
// chunk c=(i*64+lane) holds A[row=i*16+(lane&15)][k=(lane>>4)*8 ..+8].
__global__ __launch_bounds__(512, 4) void k_h1(
    const float* __restrict__ x, const float* __restrict__ u,
    const float* __restrict__ basis, const float* __restrict__ W1,
    const float* __restrict__ b1, const u16* __restrict__ W1frag,
    u16* __restrict__ h1) {
    __shared__ u16 As[2][2][2048];        // 16 KB: [buf][tile][chunk*8]
    __shared__ floatx4 redbuf[2048];      // 32 KB: k-split reduce
    __shared__ float rowsml[64][6];
    __shared__ float colsml[256][6];

    const int t = threadIdx.x;
    const int b = blockIdx.y;
    const int i0 = blockIdx.x * 64;
    const int lane = t & 63, wv = t >> 6;
    const int lr = lane & 15, lq = lane >> 4;
    const int k2 = wv & 1, n4 = wv >> 1;

    if (t < 256) {
        int c = t;
        float u0 = u[b * 2 + 0], u1 = u[b * 2 + 1];
        colsml[c][0] = b1[c] + u0 * W1[c] + u1 * W1[256 + c];
        colsml[c][1] = W1[512 + c];
        colsml[c][2] = W1[768 + c];
        colsml[c][3] = W1[1024 + c];
        colsml[c][4] = W1[1280 + c];
        colsml[c][5] = W1[1536 + c];
    }
    if (t < 64) {
        const float* xp = x + (b * 2048 + i0 + t) * 3;
        float xx = xp[0], xy = xp[1], xz = xp[2];
        rowsml[t][0] = sqrtf(xx * xx + xy * xy + xz * xz);
#pragma unroll
        for (int p = 0; p < 4; ++p) {
            const float* bp = basis + (b * 4 + p) * 3;
            rowsml[t][1 + p] = xx * bp[0] + xy * bp[1] + xz * bp[2];
        }
    }

    // gen thread mapping: tile m = t>>8, chunk c = t&255
    const int gm = t >> 8, gc = t & 255;
    const int grow = ((gc >> 6) * 16) + (gc & 15);
    const float* ap = x + (b * 2048 + i0 + grow) * 3;
    const float gax = ap[0], gay = ap[1], gaz = ap[2];
    const float* xbase = x + b * 6144;
    const int gk = ((gc >> 4) & 3) * 8;   // k-offset within 32-tile

    auto gen = [&](int ktbase, int bufsel) {
        const float4* px = (const float4*)(xbase + ((ktbase + gm) * 32 + gk) * 3);
        float4 p0 = px[0], p1 = px[1], p2 = px[2];
        float s0 = __builtin_amdgcn_sqrtf(gax * p0.x + gay * p0.y + gaz * p0.z);
        float s1 = __builtin_amdgcn_sqrtf(gax * p0.w + gay * p1.x + gaz * p1.y);
        float s2 = __builtin_amdgcn_sqrtf(gax * p1.z + gay * p1.w + gaz * p2.x);
        float s3 = __builtin_amdgcn_sqrtf(gax * p2.y + gay * p2.z + gaz * p2.w);
        u32 d0 = pack2bf(s0, s1), d1 = pack2bf(s2, s3);
        float4 p3 = px[3], p4 = px[4], p5 = px[5];
        float s4 = __builtin_amdgcn_sqrtf(gax * p3.x + gay * p3.y + gaz * p3.z);
        float s5 = __builtin_amdgcn_sqrtf(gax * p3.w + gay * p4.x + gaz * p4.y);
        float s6 = __builtin_amdgcn_sqrtf(gax * p4.z + gay * p4.w + gaz * p5.x);
        float s7 = __builtin_amdgcn_sqrtf(gax * p5.y + gay * p5.z + gaz * p5.w);
        uint4 dv;
        dv.x = d0; dv.y = d1;
        dv.z = pack2bf(s4, s5); dv.w = pack2bf(s6, s7);
        *(uint4*)&As[bufsel][gm][gc * 8] = dv;   // lane-consecutive 16B
    };

    floatx4 acc[4][4];
    const floatx4 zero = {0.f, 0.f, 0.f, 0.f};
#pragma unroll
    for (int i = 0; i < 4; ++i)
#pragma unroll
        for (int f = 0; f < 4; ++f) acc[i][f] = zero;

    gen(0, 0);
    __syncthreads();

    for (int r = 0; r < 32; ++r) {
        const int buf = r & 1;
        const int kt = 2 * r + k2;
        short8 acur[4], bcur[4];
#pragma unroll
        for (int i = 0; i < 4; ++i)
            acur[i] = *(const short8*)&As[buf][k2][(i * 64 + lane) * 8];
        const u16* bp = W1frag + ((kt * 4 + n4) * 64 + lane) * 32;
#pragma unroll
        for (int f = 0; f < 4; ++f) bcur[f] = *(const short8*)(bp + f * 8);
        if (r < 31) gen(2 * r + 2, buf ^ 1);
#pragma unroll
        for (int i = 0; i < 4; ++i)
#pragma unroll
            for (int f = 0; f < 4; ++f)
                acc[i][f] = mfma16(acur[i], bcur[f], acc[i][f]);
        __syncthreads();
    }

    // k-split reduce: odd-k2 waves push, even-k2 add (two 16KB passes)
#pragma unroll
    for (int half = 0; half < 2; ++half) {
        if (k2 == 1) {
#pragma unroll
            for (int iL = 0; iL < 2; ++iL)
#pragma unroll
                for (int f = 0; f < 4; ++f)
                    redbuf[(n4 * 8 + iL * 4 + f) * 64 + lane] = acc[half * 2 + iL][f];
        }
        __syncthreads();
        if (k2 == 0) {
#pragma unroll
            for (int iL = 0; iL < 2; ++iL)
#pragma unroll
                for (int f = 0; f < 4; ++f) {
                    floatx4 v = redbuf[(n4 * 8 + iL * 4 + f) * 64 + lane];
                    acc[half * 2 + iL][f] += v;
                }
        }
        __syncthreads();
    }

    if (k2 == 0) {
#pragma unroll
        for (int i = 0; i < 4; ++i) {
#pragma unroll
            for (int r2 = 0; r2 < 4; ++r2) {
                int row = i * 16 + lq * 4 + r2;
                float nrm = rowsml[row][0];
                float p0 = rowsml[row][1], p1 = rowsml[row][2];
                float p2 = rowsml[row][3], p3 = rowsml[row][4];
                u16* orow = h1 + (b * 2048 + i0 + row) * 256;
#pragma unroll
                for (int f = 0; f < 4; ++f) {
                    int col = n4 * 64 + f * 16 + lr;
                    float v = acc[i][f][r2] + colsml[col][0] + nrm * colsml[col][1] +
                              p0 * colsml[col][2] + p1 * colsml[col][3] +
                              p2 * colsml[col][4] + p3 * colsml[col][5];
                    v = v > 0.f ? v : 0.01f * v;
                    orow[col] = f2bf(v);
                }
            }
        }
    }
}

// ---- fused tail: h2 = lrelu(h1@W2+b2) (LDS), fk = h2@W3+b3, x-reduce.
// 4 blocks/CU; phase1 barrier-free (global A + W2frag stream).
__global__ __launch_bounds__(256, 4) void k_tail(
    const u16* __restrict__ h1, const u16* __restrict__ W2frag,
    const float* __restrict__ b2, const u16* __restrict__ W3frag,
    const float* __restrict__ b3, const float* __restrict__ x,
    float* __restrict__ accum) {
    __shared__ u16 h2s[64][260];    // stride 260: b64-aligned frag reads, ~4-way max
    __shared__ float colb2[256];
    __shared__ float colb3[128];
    __shared__ float xs[64][4];
    __shared__ float red[128][4];

    const int t = threadIdx.x;
    const int m0 = blockIdx.x * 64;
    const int b = m0 >> 11, i0 = m0 & 2047;
    const int lane = t & 63, wv = t >> 6;
    const int lr = lane & 15, lq = lane >> 4;

    colb2[t] = b2[t];
    if (t < 128) colb3[t] = b3[t];
    if (t < 64) {
        const float* xp = x + (b * 2048 + i0 + t) * 3;
        xs[t][0] = xp[0]; xs[t][1] = xp[1]; xs[t][2] = xp[2];
    }

    // ---- phase 1
    floatx4 acc[4][4];
    const floatx4 zero = {0.f, 0.f, 0.f, 0.f};
#pragma unroll
    for (int i = 0; i < 4; ++i)
#pragma unroll
        for (int j = 0; j < 4; ++j) acc[i][j] = zero;

    const u16* hsrc = h1 + m0 * 256 + lr * 256 + lq * 8;
    const u16* w2s = W2frag + t * 32;
#pragma unroll 2
    for (int kt = 0; kt < 8; ++kt) {
        short8 af[4], bf[4];
#pragma unroll
        for (int i = 0; i < 4; ++i)
            af[i] = *(const short8*)(hsrc + i * 4096 + kt * 32);
#pragma unroll
        for (int j = 0; j < 4; ++j)
            bf[j] = *(const short8*)(w2s + kt * 8192 + j * 8);
#pragma unroll
        for (int i = 0; i < 4; ++i)
#pragma unroll
            for (int j = 0; j < 4; ++j) acc[i][j] = mfma16(af[i], bf[j], acc[i][j]);
    }
#pragma unroll
    for (int i = 0; i < 4; ++i)
#pragma unroll
        for (int r = 0; r < 4; ++r) {
            int row = i * 16 + lq * 4 + r;
#pragma unroll
            for (int j = 0; j < 4; ++j) {
                int col = wv * 64 + j * 16 + lr;
                float v = acc[i][j][r] + colb2[col];
                v = v > 0.f ? v : 0.01f * v;
                h2s[row][col] = f2bf(v);
            }
        }
    __syncthreads();

    // ---- phase 2
    floatx4 acc2[4][2];
#pragma unroll
    for (int i = 0; i < 4; ++i)
#pragma unroll
        for (int j = 0; j < 2; ++j) acc2[i][j] = zero;

    const u16* w3s = W3frag + t * 16;
#pragma unroll 2
    for (int kt = 0; kt < 8; ++kt) {
        short8 af[4], bf[2];
#pragma unroll
        for (int i = 0; i < 4; ++i) {
            union { short8 s; uint2 u2[2]; } afu;
            afu.u2[0] = *(const uint2*)&h2s[i * 16 + lr][kt * 32 + lq * 8];
            afu.u2[1] = *(const uint2*)&h2s[i * 16 + lr][kt * 32 + lq * 8 + 4];
            af[i] = afu.s;
        }
#pragma unroll
        for (int j = 0; j < 2; ++j)
            bf[j] = *(const short8*)(w3s + kt * 4096 + j * 8);
#pragma unroll
        for (int i = 0; i < 4; ++i)
#pragma unroll
            for (int j = 0; j < 2; ++j) acc2[i][j] = mfma16(af[i], bf[j], acc2[i][j]);
    }

    float s[2][3];
#pragma unroll
    for (int j = 0; j < 2; ++j) { s[j][0] = 0.f; s[j][1] = 0.f; s[j][2] = 0.f; }
#pragma unroll
    for (int i = 0; i < 4; ++i)
#pragma unroll
        for (int r = 0; r < 4; ++r) {
            int row = i * 16 + lq * 4 + r;
            float x0 = xs[row][0], x1 = xs[row][1], x2 = xs[row][2];
#pragma unroll
            for (int j = 0; j < 2; ++j) {
                int col = wv * 32 + j * 16 + lr;
                float fk = acc2[i][j][r] + colb3[col];
                s[j][0] += fk * x0; s[j][1] += fk * x1; s[j][2] += fk * x2;
            }
        }
#pragma unroll
    for (int j = 0; j < 2; ++j)
#pragma unroll
        for (int d = 0; d < 3; ++d) {
            float v = s[j][d];
            v += __shfl_xor(v, 16);
            v += __shfl_xor(v, 32);
            if (lane < 16) red[wv * 32 + j * 16 + lane][d] = v;  // wave-exclusive cols
        }
    __syncthreads();
    if (t < 128) {
#pragma unroll
        for (int d = 0; d < 3; ++d)
            atomicAdd(&accum[(b * 128 + t) * 3 + d], red[t][d]);
    }
}

__global__ void k_fin(const float* __restrict__ accum, float* __restrict__ out) {
    int idx = blockIdx.x * 256 + threadIdx.x;
    if (idx < 6144) out[idx] = accum[idx] * (1.0f / 2048.0f);
}

extern "C" void kernel_launch(void* const* d_in, const int* in_sizes, int n_in,
                              void* d_out, int out_size, void* d_ws, size_t ws_size,
                              hipStream_t stream) {
    const float* x     = (const float*)d_in[0];
    const float* u     = (const float*)d_in[1];
    const float* basis = (const float*)d_in[2];
    const float* W1    = (const float*)d_in[3];
    const float* b1    = (const float*)d_in[4];
    const float* W2    = (const float*)d_in[5];
    const float* b2    = (const float*)d_in[6];
    const float* W3    = (const float*)d_in[7];
    const float* b3    = (const float*)d_in[8];
    float* out = (float*)d_out;

    char* ws = (char*)d_ws;
    u16*  W1frag = (u16*)ws;                      // 1,048,576 B
    u16*  W2frag = (u16*)(ws + 1048576);          //   131,072 B
    u16*  W3frag = (u16*)(ws + 1179648);          //    65,536 B
    u16*  h1     = (u16*)(ws + 1245184);          // 16,777,216 B
    float* accum = (float*)(ws + 18022400);       //    24,576 B

    hipMemsetAsync(accum, 0, 24576, stream);
    k_prep<<<80, 256, 0, stream>>>(W1, W2, W3, W1frag, W2frag, W3frag);
    k_h1<<<dim3(32, 16), 512, 0, stream>>>(x, u, basis, W1, b1, W1frag, h1);
    k_tail<<<512, 256, 0, stream>>>(h1, W2frag, b2, W3frag, b3, x, accum);
    k_fin<<<24, 256, 0, stream>>>(accum, out);
}